// Round 9
// baseline (1416.689 us; speedup 1.0000x reference)
//
#include <hip/hip_runtime.h>

#define N_NODES 100000
#define N_EDGES 1600000
#define BSHIFT 6
#define BNODES 64            // nodes per bucket
#define NB 1563              // ceil(100000/64)
#define NBP 1568             // padded (multiple of 32)
#define GCHUNK 512

typedef short bf16x8 __attribute__((ext_vector_type(8)));
typedef float f32x4 __attribute__((ext_vector_type(4)));

// ---------------- threefry2x32 (exact JAX semantics) ----------------
struct KeyPair { unsigned a, b; };

__host__ __device__ constexpr unsigned rotl32c(unsigned x, int d) {
    return (x << d) | (x >> (32 - d));
}

__host__ __device__ constexpr KeyPair threefry2x32(unsigned k0, unsigned k1,
                                                   unsigned x0, unsigned x1) {
    unsigned ks0 = k0, ks1 = k1, ks2 = 0x1BD11BDAu ^ k0 ^ k1;
    const int rot0[4] = {13, 15, 26, 6};
    const int rot1[4] = {17, 29, 16, 24};
    x0 += ks0; x1 += ks1;
    for (int i = 0; i < 4; ++i) { x0 += x1; x1 = rotl32c(x1, rot0[i]); x1 ^= x0; }
    x0 += ks1; x1 += ks2 + 1u;
    for (int i = 0; i < 4; ++i) { x0 += x1; x1 = rotl32c(x1, rot1[i]); x1 ^= x0; }
    x0 += ks2; x1 += ks0 + 2u;
    for (int i = 0; i < 4; ++i) { x0 += x1; x1 = rotl32c(x1, rot0[i]); x1 ^= x0; }
    x0 += ks0; x1 += ks1 + 3u;
    for (int i = 0; i < 4; ++i) { x0 += x1; x1 = rotl32c(x1, rot1[i]); x1 ^= x0; }
    x0 += ks1; x1 += ks2 + 4u;
    for (int i = 0; i < 4; ++i) { x0 += x1; x1 = rotl32c(x1, rot0[i]); x1 ^= x0; }
    x0 += ks2; x1 += ks0 + 5u;
    return {x0, x1};
}

constexpr KeyPair FKEY = threefry2x32(0u, 42u, 0u, 7u);

// partitionable threefry bits: b1^b2 of threefry(key, (0, e))
__device__ __forceinline__ float dropout_val(float xv, unsigned e) {
    KeyPair o = threefry2x32(FKEY.a, FKEY.b, 0u, e);
    unsigned bits = o.a ^ o.b;
    float u = __uint_as_float((bits >> 9) | 0x3f800000u) - 1.0f;
    return (u < 0.9f) ? xv * (1.0f / 0.9f) : 0.0f;
}

// fp32 -> bf16 RTNE
__device__ __forceinline__ unsigned short f2bf(float f) {
    unsigned u = __float_as_uint(f);
    unsigned r = (u + 0x7FFFu + ((u >> 16) & 1u)) >> 16;
    return (unsigned short)r;
}

// ---------------- W -> bf16, transposed + XOR-swizzled (wt[n][k]) ----------
__global__ __launch_bounds__(256) void wconv_kernel(
        const float* __restrict__ w, char* __restrict__ wt) {
    int id = blockIdx.x * 256 + threadIdx.x;   // 16384 = 128*128
    int k = id >> 7;
    int n = id & 127;
    unsigned short b = f2bf(w[k * 128 + n]);
    unsigned byte = ((unsigned)(n * 256 + k * 2)) ^ ((unsigned)((n & 7) << 4));
    *(unsigned short*)(wt + byte) = b;
}

// ---------------- fused dropout + MFMA GEMM, h in bf16 ----------------
__global__ __launch_bounds__(256) void gemm_dropout_kernel(
        const float* __restrict__ x, const char* __restrict__ wt,
        unsigned short* __restrict__ h) {
    __shared__ __align__(16) char smem[49152];  // [0,16K): A 64x128 swz; [16K,48K): B^T swz
    const int t = threadIdx.x;
    const int r0 = blockIdx.x * 64;

    #pragma unroll
    for (int i = 0; i < 8; ++i) {
        int off = t * 16 + i * 4096;
        *(uint4*)(smem + 16384 + off) = *(const uint4*)(wt + off);
    }

    {
        const int row = t >> 2;
        const int ks  = (t & 3) * 32;
        const int grow = r0 + row;
        const bool valid = grow < N_NODES;
        float xv[32];
        #pragma unroll
        for (int q = 0; q < 8; ++q) {
            float4 v = valid ? *(const float4*)(x + (size_t)grow * 128 + ks + q * 4)
                             : make_float4(0.f, 0.f, 0.f, 0.f);
            xv[q * 4 + 0] = v.x; xv[q * 4 + 1] = v.y;
            xv[q * 4 + 2] = v.z; xv[q * 4 + 3] = v.w;
        }
        const unsigned ebase = (unsigned)grow * 128u + (unsigned)ks;
        #pragma unroll
        for (int q = 0; q < 4; ++q) {
            unsigned pk[4];
            #pragma unroll
            for (int p = 0; p < 4; ++p) {
                float a = dropout_val(xv[q * 8 + p * 2],     ebase + q * 8 + p * 2);
                float b = dropout_val(xv[q * 8 + p * 2 + 1], ebase + q * 8 + p * 2 + 1);
                pk[p] = (unsigned)f2bf(a) | ((unsigned)f2bf(b) << 16);
            }
            unsigned byte = ((unsigned)(row * 256 + (ks + q * 8) * 2))
                            ^ ((unsigned)((row & 7) << 4));
            *(uint4*)(smem + byte) = *(uint4*)pk;
        }
    }
    __syncthreads();

    const int wv = t >> 6;
    const int l  = t & 63;
    const int lm = l & 15;
    const int lg = l >> 4;
    const int arow = wv * 16 + lm;
    const unsigned axor = (unsigned)((arow & 7) << 4);
    const unsigned aoff = (unsigned)(arow * 256 + lg * 16);
    const unsigned bxor = (unsigned)((lm & 7) << 4);
    const unsigned boff = (unsigned)(lm * 256 + lg * 16);

    f32x4 acc[8] = {};
    #pragma unroll
    for (int kc = 0; kc < 4; ++kc) {
        bf16x8 af = *(const bf16x8*)(smem + ((aoff + kc * 64) ^ axor));
        #pragma unroll
        for (int nt = 0; nt < 8; ++nt) {
            bf16x8 bf = *(const bf16x8*)(smem + 16384 + nt * 4096
                                         + ((boff + kc * 64) ^ bxor));
            acc[nt] = __builtin_amdgcn_mfma_f32_16x16x32_bf16(af, bf, acc[nt], 0, 0, 0);
        }
    }

    const int orow0 = r0 + wv * 16 + lg * 4;
    #pragma unroll
    for (int nt = 0; nt < 8; ++nt) {
        const int col = nt * 16 + lm;
        #pragma unroll
        for (int r2 = 0; r2 < 4; ++r2) {
            const int row = orow0 + r2;
            if (row < N_NODES) h[(size_t)row * 128 + col] = f2bf(acc[nt][r2]);
        }
    }
}

// ---------------- coarse bucket CSR: hist -> scan -> scatter ----------------
__global__ __launch_bounds__(256) void bucket_hist_kernel(
        const int* __restrict__ edst, int* __restrict__ ghist) {
    __shared__ int lh[NBP];
    for (int i = threadIdx.x; i < NBP; i += 256) lh[i] = 0;
    __syncthreads();
    const int chunk = (N_EDGES + gridDim.x - 1) / gridDim.x;
    const int b0 = blockIdx.x * chunk;
    const int b1 = min(b0 + chunk, N_EDGES);
    for (int e = b0 + threadIdx.x; e < b1; e += 256)
        atomicAdd(&lh[edst[e] >> BSHIFT], 1);
    __syncthreads();
    for (int i = threadIdx.x; i < NBP; i += 256)
        if (lh[i]) atomicAdd(&ghist[i], lh[i]);
}

// exclusive scan over NBP=1568 entries: 1024 threads, 2 elems/thread
__global__ __launch_bounds__(1024) void bucket_scan_kernel(
        const int* __restrict__ ghist, int* __restrict__ gbase,
        int* __restrict__ gcursor) {
    __shared__ int sc[1024];
    const int t = threadIdx.x;
    int v0 = (2 * t < NBP) ? ghist[2 * t] : 0;
    int v1 = (2 * t + 1 < NBP) ? ghist[2 * t + 1] : 0;
    sc[t] = v0 + v1;
    __syncthreads();
    for (int off = 1; off < 1024; off <<= 1) {
        int u = (t >= off) ? sc[t - off] : 0;
        __syncthreads();
        sc[t] += u;
        __syncthreads();
    }
    int incl = sc[t];
    int excl = incl - (v0 + v1);
    if (2 * t < NBP) {
        gbase[2 * t] = excl;
        gcursor[2 * t] = excl;
    }
    if (2 * t + 1 < NBP) {
        gbase[2 * t + 1] = excl + v0;
        gcursor[2 * t + 1] = excl + v0;
    }
}

__global__ __launch_bounds__(256) void bucket_scatter_kernel(
        const int* __restrict__ esrc, const int* __restrict__ edst,
        const float* __restrict__ evals, int* __restrict__ gcursor,
        int2* __restrict__ spack) {
    __shared__ int lh[NBP];
    __shared__ int lbase[NBP];
    for (int i = threadIdx.x; i < NBP; i += 256) lh[i] = 0;
    __syncthreads();
    const int chunk = (N_EDGES + gridDim.x - 1) / gridDim.x;
    const int b0 = blockIdx.x * chunk;
    const int b1 = min(b0 + chunk, N_EDGES);
    for (int e = b0 + threadIdx.x; e < b1; e += 256)
        atomicAdd(&lh[edst[e] >> BSHIFT], 1);
    __syncthreads();
    for (int i = threadIdx.x; i < NBP; i += 256) {
        int c = lh[i];
        lbase[i] = c ? atomicAdd(&gcursor[i], c) : 0;
        lh[i] = 0;   // reuse as local cursor
    }
    __syncthreads();
    for (int e = b0 + threadIdx.x; e < b1; e += 256) {
        int d = edst[e];
        int b = d >> BSHIFT;
        int r = atomicAdd(&lh[b], 1);
        int2 p;
        p.x = esrc[e] | ((d & (BNODES - 1)) << 20);   // src (20b) | dst_local (6b)
        p.y = __float_as_int(evals[e]);
        spack[lbase[b] + r] = p;
    }
}

// ---------------- bucket gather: LDS accumulate + fused ReLU ----------------
// 36 KB LDS/block -> 4 blocks/CU
__global__ __launch_bounds__(256) void bucket_gather_kernel(
        const unsigned short* __restrict__ h, const int* __restrict__ gbase,
        const int2* __restrict__ spack, float* __restrict__ out) {
    __shared__ float acc[BNODES * 128];   // 32 KB: [node_local][dim]
    __shared__ int2 ebuf[GCHUNK];         //  4 KB
    const int t = threadIdx.x;
    const int b = blockIdx.x;

    #pragma unroll
    for (int i = 0; i < 8; ++i) {
        f32x4 z = {0.f, 0.f, 0.f, 0.f};
        *(f32x4*)&acc[(t + i * 256) * 4] = z;
    }

    const int start = gbase[b];
    const int end = gbase[b + 1];
    const int w = t >> 6;
    const int l = t & 63;

    for (int cbase = start; cbase < end; cbase += GCHUNK) {
        const int n = min(GCHUNK, end - cbase);
        __syncthreads();   // protect ebuf from previous chunk's readers / acc init
        for (int i = t; i < n; i += 256) ebuf[i] = spack[cbase + i];
        __syncthreads();
        const int per = (n + 3) >> 2;
        const int js = w * per;
        const int je = min(js + per, n);
        #pragma unroll 4
        for (int j = js; j < je; ++j) {
            int2 p = ebuf[j];
            float val = __int_as_float(p.y);
            int src = p.x & 0xFFFFF;
            int dl = p.x >> 20;
            const unsigned short* hr = h + (size_t)src * 128;
            float h0 = __uint_as_float(((unsigned)hr[l]) << 16);
            float h1 = __uint_as_float(((unsigned)hr[l + 64]) << 16);
            atomicAdd(&acc[dl * 128 + l],      val * h0);
            atomicAdd(&acc[dl * 128 + l + 64], val * h1);
        }
    }
    __syncthreads();

    const int node0 = b * BNODES;
    #pragma unroll
    for (int i = 0; i < 8; ++i) {
        int idx = t + i * 256;          // float4 index (32 per row)
        int node = node0 + (idx >> 5);
        if (node < N_NODES) {
            float4 v = ((float4*)acc)[idx];
            v.x = fmaxf(v.x, 0.f);
            v.y = fmaxf(v.y, 0.f);
            v.z = fmaxf(v.z, 0.f);
            v.w = fmaxf(v.w, 0.f);
            ((float4*)(out + (size_t)node * 128))[idx & 31] = v;
        }
    }
}

extern "C" void kernel_launch(void* const* d_in, const int* in_sizes, int n_in,
                              void* d_out, int out_size, void* d_ws, size_t ws_size,
                              hipStream_t stream) {
    const float* x     = (const float*)d_in[0];
    const float* w     = (const float*)d_in[1];
    const int*   esrc  = (const int*)d_in[2];
    const int*   edst  = (const int*)d_in[3];
    const float* evals = (const float*)d_in[4];
    float* out = (float*)d_out;

    char* ws = (char*)d_ws;
    unsigned short* h       = (unsigned short*)(ws);       // 25,600,000 B (bf16)
    int2*           spack   = (int2*)(ws + 25600000);      // 12,800,000 B
    int*            ghist   = (int*)(ws + 38400000);       //      6,272 B (1568)
    int*            gbase   = (int*)(ws + 38406400);       //      6,272 B
    int*            gcursor = (int*)(ws + 38412672);       //      6,272 B
    char*           wt      = (char*)(ws + 38418944);      //     32,768 B

    hipMemsetAsync(ghist, 0, NBP * sizeof(int), stream);

    // coarse-bucket CSR build
    bucket_hist_kernel<<<128, 256, 0, stream>>>(edst, ghist);
    bucket_scan_kernel<<<1, 1024, 0, stream>>>(ghist, gbase, gcursor);
    bucket_scatter_kernel<<<128, 256, 0, stream>>>(esrc, edst, evals, gcursor, spack);

    // dense transform (bf16 MFMA)
    wconv_kernel<<<64, 256, 0, stream>>>(w, wt);
    gemm_dropout_kernel<<<(N_NODES + 63) / 64, 256, 0, stream>>>(x, wt, h);

    // bucketed aggregate + ReLU
    bucket_gather_kernel<<<NB, 256, 0, stream>>>(h, gbase, spack, out);
}

// Round 15
// 330.678 us; speedup vs baseline: 4.2842x; 4.2842x over previous
//
#include <hip/hip_runtime.h>

#define N_NODES 100000
#define N_EDGES 1600000
#define BSHIFT 6
#define BNODES 64            // nodes per bucket
#define NB 1563              // ceil(100000/64)
#define NBP 1568             // padded
#define GATHER_SLOTS 8

typedef short bf16x8 __attribute__((ext_vector_type(8)));
typedef float f32x4 __attribute__((ext_vector_type(4)));

// ---------------- threefry2x32 (exact JAX semantics) ----------------
struct KeyPair { unsigned a, b; };

__host__ __device__ constexpr unsigned rotl32c(unsigned x, int d) {
    return (x << d) | (x >> (32 - d));
}

__host__ __device__ constexpr KeyPair threefry2x32(unsigned k0, unsigned k1,
                                                   unsigned x0, unsigned x1) {
    unsigned ks0 = k0, ks1 = k1, ks2 = 0x1BD11BDAu ^ k0 ^ k1;
    const int rot0[4] = {13, 15, 26, 6};
    const int rot1[4] = {17, 29, 16, 24};
    x0 += ks0; x1 += ks1;
    for (int i = 0; i < 4; ++i) { x0 += x1; x1 = rotl32c(x1, rot0[i]); x1 ^= x0; }
    x0 += ks1; x1 += ks2 + 1u;
    for (int i = 0; i < 4; ++i) { x0 += x1; x1 = rotl32c(x1, rot1[i]); x1 ^= x0; }
    x0 += ks2; x1 += ks0 + 2u;
    for (int i = 0; i < 4; ++i) { x0 += x1; x1 = rotl32c(x1, rot0[i]); x1 ^= x0; }
    x0 += ks0; x1 += ks1 + 3u;
    for (int i = 0; i < 4; ++i) { x0 += x1; x1 = rotl32c(x1, rot1[i]); x1 ^= x0; }
    x0 += ks1; x1 += ks2 + 4u;
    for (int i = 0; i < 4; ++i) { x0 += x1; x1 = rotl32c(x1, rot0[i]); x1 ^= x0; }
    x0 += ks2; x1 += ks0 + 5u;
    return {x0, x1};
}

constexpr KeyPair FKEY = threefry2x32(0u, 42u, 0u, 7u);

// partitionable threefry bits: b1^b2 of threefry(key, (0, e))
__device__ __forceinline__ float dropout_val(float xv, unsigned e) {
    KeyPair o = threefry2x32(FKEY.a, FKEY.b, 0u, e);
    unsigned bits = o.a ^ o.b;
    float u = __uint_as_float((bits >> 9) | 0x3f800000u) - 1.0f;
    return (u < 0.9f) ? xv * (1.0f / 0.9f) : 0.0f;
}

// fp32 -> bf16 RTNE
__device__ __forceinline__ unsigned short f2bf(float f) {
    unsigned u = __float_as_uint(f);
    unsigned r = (u + 0x7FFFu + ((u >> 16) & 1u)) >> 16;
    return (unsigned short)r;
}

// ---------------- W -> bf16, transposed + XOR-swizzled (wt[n][k]) ----------
__global__ __launch_bounds__(256) void wconv_kernel(
        const float* __restrict__ w, char* __restrict__ wt) {
    int id = blockIdx.x * 256 + threadIdx.x;   // 16384 = 128*128
    int k = id >> 7;
    int n = id & 127;
    unsigned short b = f2bf(w[k * 128 + n]);
    unsigned byte = ((unsigned)(n * 256 + k * 2)) ^ ((unsigned)((n & 7) << 4));
    *(unsigned short*)(wt + byte) = b;
}

// ---------------- fused dropout + MFMA GEMM, h in bf16 ----------------
__global__ __launch_bounds__(256) void gemm_dropout_kernel(
        const float* __restrict__ x, const char* __restrict__ wt,
        unsigned short* __restrict__ h) {
    __shared__ __align__(16) char smem[49152];  // [0,16K): A 64x128 swz; [16K,48K): B^T swz
    const int t = threadIdx.x;
    const int r0 = blockIdx.x * 64;

    #pragma unroll
    for (int i = 0; i < 8; ++i) {
        int off = t * 16 + i * 4096;
        *(uint4*)(smem + 16384 + off) = *(const uint4*)(wt + off);
    }

    {
        const int row = t >> 2;
        const int ks  = (t & 3) * 32;
        const int grow = r0 + row;
        const bool valid = grow < N_NODES;
        float xv[32];
        #pragma unroll
        for (int q = 0; q < 8; ++q) {
            float4 v = valid ? *(const float4*)(x + (size_t)grow * 128 + ks + q * 4)
                             : make_float4(0.f, 0.f, 0.f, 0.f);
            xv[q * 4 + 0] = v.x; xv[q * 4 + 1] = v.y;
            xv[q * 4 + 2] = v.z; xv[q * 4 + 3] = v.w;
        }
        const unsigned ebase = (unsigned)grow * 128u + (unsigned)ks;
        #pragma unroll
        for (int q = 0; q < 4; ++q) {
            unsigned pk[4];
            #pragma unroll
            for (int p = 0; p < 4; ++p) {
                float a = dropout_val(xv[q * 8 + p * 2],     ebase + q * 8 + p * 2);
                float b = dropout_val(xv[q * 8 + p * 2 + 1], ebase + q * 8 + p * 2 + 1);
                pk[p] = (unsigned)f2bf(a) | ((unsigned)f2bf(b) << 16);
            }
            unsigned byte = ((unsigned)(row * 256 + (ks + q * 8) * 2))
                            ^ ((unsigned)((row & 7) << 4));
            *(uint4*)(smem + byte) = *(uint4*)pk;
        }
    }
    __syncthreads();

    const int wv = t >> 6;
    const int l  = t & 63;
    const int lm = l & 15;
    const int lg = l >> 4;
    const int arow = wv * 16 + lm;
    const unsigned axor = (unsigned)((arow & 7) << 4);
    const unsigned aoff = (unsigned)(arow * 256 + lg * 16);
    const unsigned bxor = (unsigned)((lm & 7) << 4);
    const unsigned boff = (unsigned)(lm * 256 + lg * 16);

    f32x4 acc[8] = {};
    #pragma unroll
    for (int kc = 0; kc < 4; ++kc) {
        bf16x8 af = *(const bf16x8*)(smem + ((aoff + kc * 64) ^ axor));
        #pragma unroll
        for (int nt = 0; nt < 8; ++nt) {
            bf16x8 bf = *(const bf16x8*)(smem + 16384 + nt * 4096
                                         + ((boff + kc * 64) ^ bxor));
            acc[nt] = __builtin_amdgcn_mfma_f32_16x16x32_bf16(af, bf, acc[nt], 0, 0, 0);
        }
    }

    const int orow0 = r0 + wv * 16 + lg * 4;
    #pragma unroll
    for (int nt = 0; nt < 8; ++nt) {
        const int col = nt * 16 + lm;
        #pragma unroll
        for (int r2 = 0; r2 < 4; ++r2) {
            const int row = orow0 + r2;
            if (row < N_NODES) h[(size_t)row * 128 + col] = f2bf(acc[nt][r2]);
        }
    }
}

// ---------------- coarse bucket CSR: hist -> scan -> scatter ----------------
__global__ __launch_bounds__(256) void bucket_hist_kernel(
        const int* __restrict__ edst, int* __restrict__ ghist) {
    __shared__ int lh[NBP];
    for (int i = threadIdx.x; i < NBP; i += 256) lh[i] = 0;
    __syncthreads();
    const int chunk = (N_EDGES + gridDim.x - 1) / gridDim.x;
    const int b0 = blockIdx.x * chunk;
    const int b1 = min(b0 + chunk, N_EDGES);
    for (int e = b0 + threadIdx.x; e < b1; e += 256)
        atomicAdd(&lh[edst[e] >> BSHIFT], 1);
    __syncthreads();
    for (int i = threadIdx.x; i < NBP; i += 256)
        if (lh[i]) atomicAdd(&ghist[i], lh[i]);
}

// exclusive scan over NBP=1568 entries
__global__ __launch_bounds__(1024) void bucket_scan_kernel(
        const int* __restrict__ ghist, int* __restrict__ gbase,
        int* __restrict__ gcursor) {
    __shared__ int sc[1024];
    const int t = threadIdx.x;
    int v0 = (2 * t < NBP) ? ghist[2 * t] : 0;
    int v1 = (2 * t + 1 < NBP) ? ghist[2 * t + 1] : 0;
    sc[t] = v0 + v1;
    __syncthreads();
    for (int off = 1; off < 1024; off <<= 1) {
        int u = (t >= off) ? sc[t - off] : 0;
        __syncthreads();
        sc[t] += u;
        __syncthreads();
    }
    int excl = sc[t] - (v0 + v1);
    if (2 * t < NBP) {
        gbase[2 * t] = excl;
        gcursor[2 * t] = excl;
    }
    if (2 * t + 1 < NBP) {
        gbase[2 * t + 1] = excl + v0;
        gcursor[2 * t + 1] = excl + v0;
    }
}

__global__ __launch_bounds__(256) void bucket_scatter_kernel(
        const int* __restrict__ esrc, const int* __restrict__ edst,
        const float* __restrict__ evals, int* __restrict__ gcursor,
        int2* __restrict__ spack) {
    __shared__ int lh[NBP];
    __shared__ int lbase[NBP];
    for (int i = threadIdx.x; i < NBP; i += 256) lh[i] = 0;
    __syncthreads();
    const int chunk = (N_EDGES + gridDim.x - 1) / gridDim.x;
    const int b0 = blockIdx.x * chunk;
    const int b1 = min(b0 + chunk, N_EDGES);
    for (int e = b0 + threadIdx.x; e < b1; e += 256)
        atomicAdd(&lh[edst[e] >> BSHIFT], 1);
    __syncthreads();
    for (int i = threadIdx.x; i < NBP; i += 256) {
        int c = lh[i];
        lbase[i] = c ? atomicAdd(&gcursor[i], c) : 0;
        lh[i] = 0;   // reuse as local cursor
    }
    __syncthreads();
    for (int e = b0 + threadIdx.x; e < b1; e += 256) {
        int d = edst[e];
        int b = d >> BSHIFT;
        int r = atomicAdd(&lh[b], 1);
        int2 p;
        p.x = esrc[e] | ((d & (BNODES - 1)) << 20);   // src (20b) | dst_local (6b)
        p.y = __float_as_int(evals[e]);
        spack[lbase[b] + r] = p;
    }
}

// ------- per-bucket local sort: bucket-major spack -> node-major spack2 -------
// one block per bucket; also emits per-node offsets. All writes within the
// bucket's contiguous ~8KB window (write-combinable).
__global__ __launch_bounds__(256) void local_sort_kernel(
        const int2* __restrict__ spack, const int* __restrict__ gbase,
        int2* __restrict__ spack2, int* __restrict__ offsets) {
    __shared__ int cnt[BNODES];
    __shared__ int off[BNODES];
    __shared__ int sc[BNODES];
    const int t = threadIdx.x;
    const int b = blockIdx.x;
    const int start = gbase[b];
    const int end = gbase[b + 1];

    if (t < BNODES) cnt[t] = 0;
    __syncthreads();
    for (int i = start + t; i < end; i += 256)
        atomicAdd(&cnt[spack[i].x >> 20], 1);
    __syncthreads();
    if (t < BNODES) sc[t] = cnt[t];
    __syncthreads();
    #pragma unroll
    for (int o = 1; o < BNODES; o <<= 1) {
        int u = (t >= o && t < BNODES) ? sc[t - o] : 0;
        __syncthreads();
        if (t < BNODES) sc[t] += u;
        __syncthreads();
    }
    if (t < BNODES) {
        off[t] = sc[t] - cnt[t];          // exclusive within bucket
        int nd = b * BNODES + t;
        if (nd <= N_NODES) offsets[nd] = start + off[t];
        cnt[t] = 0;                       // reuse as cursor
    }
    __syncthreads();
    for (int i = start + t; i < end; i += 256) {
        int2 p = spack[i];
        int dl = p.x >> 20;
        int r = atomicAdd(&cnt[dl], 1);
        int2 q;
        q.x = p.x & 0xFFFFF;   // pure src
        q.y = p.y;
        spack2[start + off[dl] + r] = q;
    }
}

// ---------------- per-node gather + fused ReLU (bf16 h) ----------------
__global__ __launch_bounds__(256) void gather_kernel(
        const unsigned short* __restrict__ h, const int* __restrict__ offsets,
        const int2* __restrict__ spack2, float* __restrict__ out) {
    __shared__ float red[GATHER_SLOTS][128];
    const int node = blockIdx.x;
    const int t = threadIdx.x;
    const int s = t >> 5;
    const int lane = t & 31;
    const int d4 = lane * 4;
    const int start = offsets[node];
    const int end = offsets[node + 1];

    float a0 = 0.f, a1 = 0.f, a2 = 0.f, a3 = 0.f;
    for (int j = start + s; j < end; j += GATHER_SLOTS) {
        int2 p = spack2[j];
        float val = __int_as_float(p.y);
        uint2 hv = *(const uint2*)(h + (size_t)p.x * 128 + d4);
        float h0 = __uint_as_float((hv.x & 0xFFFFu) << 16);
        float h1 = __uint_as_float(hv.x & 0xFFFF0000u);
        float h2 = __uint_as_float((hv.y & 0xFFFFu) << 16);
        float h3 = __uint_as_float(hv.y & 0xFFFF0000u);
        a0 += val * h0; a1 += val * h1; a2 += val * h2; a3 += val * h3;
    }
    float4 r; r.x = a0; r.y = a1; r.z = a2; r.w = a3;
    *reinterpret_cast<float4*>(&red[s][d4]) = r;
    __syncthreads();

    if (t < 128) {
        float acc = 0.f;
        #pragma unroll
        for (int ss = 0; ss < GATHER_SLOTS; ++ss) acc += red[ss][t];
        out[node * 128 + t] = fmaxf(acc, 0.f);
    }
}

extern "C" void kernel_launch(void* const* d_in, const int* in_sizes, int n_in,
                              void* d_out, int out_size, void* d_ws, size_t ws_size,
                              hipStream_t stream) {
    const float* x     = (const float*)d_in[0];
    const float* w     = (const float*)d_in[1];
    const int*   esrc  = (const int*)d_in[2];
    const int*   edst  = (const int*)d_in[3];
    const float* evals = (const float*)d_in[4];
    float* out = (float*)d_out;

    char* ws = (char*)d_ws;
    unsigned short* h       = (unsigned short*)(ws);       // 25,600,000 B (bf16)
    int2*           spack   = (int2*)(ws + 25600000);      // 12,800,000 B
    int2*           spack2  = (int2*)(ws + 38400000);      // 12,800,000 B
    int*            offsets = (int*)(ws + 51200000);       //    400,128 B
    int*            ghist   = (int*)(ws + 51600128);       //      6,272 B
    int*            gbase   = (int*)(ws + 51606400);       //      6,272 B
    int*            gcursor = (int*)(ws + 51612672);       //      6,272 B
    char*           wt      = (char*)(ws + 51618944);      //     32,768 B

    hipMemsetAsync(ghist, 0, NBP * sizeof(int), stream);

    // two-level CSR build: bucket scatter, then in-bucket node sort
    bucket_hist_kernel<<<128, 256, 0, stream>>>(edst, ghist);
    bucket_scan_kernel<<<1, 1024, 0, stream>>>(ghist, gbase, gcursor);
    bucket_scatter_kernel<<<128, 256, 0, stream>>>(esrc, edst, evals, gcursor, spack);
    local_sort_kernel<<<NB, 256, 0, stream>>>(spack, gbase, spack2, offsets);

    // dense transform (bf16 MFMA)
    wconv_kernel<<<64, 256, 0, stream>>>(w, wt);
    gemm_dropout_kernel<<<(N_NODES + 63) / 64, 256, 0, stream>>>(x, wt, h);

    // per-node aggregate + ReLU
    gather_kernel<<<N_NODES, 256, 0, stream>>>(h, offsets, spack2, out);
}